// Round 11
// baseline (517.571 us; speedup 1.0000x reference)
//
#include <hip/hip_runtime.h>

// Problem constants: N_A=N_B=30000, V=2, D=128
#define D 128
#define NODE_ROW 256       // V*D elements per node

typedef __attribute__((ext_vector_type(8))) short short8;
typedef __attribute__((ext_vector_type(4))) float floatx4;

__device__ __forceinline__ ushort f2bf(float f) {
    unsigned int u = __float_as_uint(f);
    u += 0x7fffu + ((u >> 16) & 1u);
    return (ushort)(u >> 16);
}
__device__ __forceinline__ unsigned int pk2(float a, float b) {
    return (unsigned int)f2bf(a) | ((unsigned int)f2bf(b) << 16);
}
__device__ __forceinline__ float bf2f(ushort h) {
    return __uint_as_float(((unsigned int)h) << 16);
}
__device__ __forceinline__ short8 ldfrag(const ushort* p) {
    union { uint4 u; short8 s; } cv;
    cv.u = *(const uint4*)p;
    return cv.s;
}
__device__ __forceinline__ void acc4(float4& a, float w, uint2 u) {
    a.x += w * __uint_as_float(u.x << 16);
    a.y += w * __uint_as_float(u.x & 0xffff0000u);
    a.z += w * __uint_as_float(u.y << 16);
    a.w += w * __uint_as_float(u.y & 0xffff0000u);
}

// ---------------- fp32 -> bf16 feature convert (both matrices, one launch) ----------------
__global__ __launch_bounds__(256) void k_f2b2(
    const float* __restrict__ srcA, const float* __restrict__ srcB,
    ushort* __restrict__ dstA, ushort* __restrict__ dstB, int n8) {
    int i = blockIdx.x * 256 + threadIdx.x;
    const float* s; ushort* d; int k;
    if (i < n8) { s = srcA; d = dstA; k = i; }
    else if (i < 2 * n8) { s = srcB; d = dstB; k = i - n8; }
    else return;
    const float4* sp = (const float4*)s + (size_t)k * 2;
    float4 a = sp[0], b = sp[1];
    uint4 o;
    o.x = pk2(a.x, a.y); o.y = pk2(a.z, a.w);
    o.z = pk2(b.x, b.y); o.w = pk2(b.z, b.w);
    ((uint4*)d)[k] = o;
}

// ---------------- CSR build ----------------

__global__ __launch_bounds__(256) void k_hist(
    const int* __restrict__ dst_ab, const int* __restrict__ dst_ba,
    int* __restrict__ cnt_ab, int* __restrict__ cnt_ba, int E) {
    int i = blockIdx.x * 256 + threadIdx.x;
    if (i >= E) return;
    atomicAdd(&cnt_ab[dst_ab[i]], 1);
    atomicAdd(&cnt_ba[dst_ba[i]], 1);
}

__global__ __launch_bounds__(1024) void k_scan2(
    int* __restrict__ cntB, int* __restrict__ startB, int nB_,
    int* __restrict__ cntA, int* __restrict__ startA, int nA_) {
    __shared__ int part[1024];
    int* cnt; int* start; int n;
    if (blockIdx.x == 0) { cnt = cntB; start = startB; n = nB_; }
    else                 { cnt = cntA; start = startA; n = nA_; }
    int t = threadIdx.x;
    int chunk = (n + 1023) >> 10;
    int lo = min(t * chunk, n), hi = min(lo + chunk, n);
    int s = 0;
    for (int i = lo; i < hi; i++) s += cnt[i];
    part[t] = s;
    __syncthreads();
    for (int d = 1; d < 1024; d <<= 1) {
        int v = (t >= d) ? part[t - d] : 0;
        __syncthreads();
        part[t] += v;
        __syncthreads();
    }
    int off = part[t] - s;
    for (int i = lo; i < hi; i++) {
        int c = cnt[i];
        start[i] = off;
        cnt[i] = off;          // running cursor for k_scatter
        off += c;
    }
    if (t == 1023) start[n] = off;
}

__global__ __launch_bounds__(256) void k_scatter(
    const int* __restrict__ src_ab, const int* __restrict__ dst_ab,
    const float* __restrict__ val_ab,
    const int* __restrict__ src_ba, const int* __restrict__ dst_ba,
    const float* __restrict__ val_ba,
    int* __restrict__ cur_ab, int* __restrict__ cur_ba,
    int2* __restrict__ ep_ab, int2* __restrict__ ep_ba, int E) {
    int i = blockIdx.x * 256 + threadIdx.x;
    if (i >= E) return;
    {
        int pos = atomicAdd(&cur_ab[dst_ab[i]], 1);
        ep_ab[pos] = make_int2(src_ab[i], __float_as_int(val_ab[i]));
    }
    {
        int pos = atomicAdd(&cur_ba[dst_ba[i]], 1);
        ep_ba[pos] = make_int2(src_ba[i], __float_as_int(val_ba[i]));
    }
}

// ---------------- pass 1 gather: aggregate fbA over ab edges, l2norm -> hB ----------------
__global__ __launch_bounds__(256) void k_gather_norm_bf(
    const ushort* __restrict__ feat, const int2* __restrict__ ep,
    const int* __restrict__ start, ushort* __restrict__ out, int n) {
    int node = blockIdx.x * 4 + (threadIdx.x >> 6);
    if (node >= n) return;
    int lane = threadIdx.x & 63;
    int lo = start[node], hi = start[node + 1];
    float4 acc = make_float4(0.f, 0.f, 0.f, 0.f);
    int i = lo;
    for (; i + 3 < hi; i += 4) {
        int2 p0 = ep[i], p1 = ep[i + 1], p2 = ep[i + 2], p3 = ep[i + 3];
        uint2 u0 = ((const uint2*)(feat + (size_t)p0.x * NODE_ROW))[lane];
        uint2 u1 = ((const uint2*)(feat + (size_t)p1.x * NODE_ROW))[lane];
        uint2 u2 = ((const uint2*)(feat + (size_t)p2.x * NODE_ROW))[lane];
        uint2 u3 = ((const uint2*)(feat + (size_t)p3.x * NODE_ROW))[lane];
        acc4(acc, __int_as_float(p0.y), u0);
        acc4(acc, __int_as_float(p1.y), u1);
        acc4(acc, __int_as_float(p2.y), u2);
        acc4(acc, __int_as_float(p3.y), u3);
    }
    for (; i < hi; i++) {
        int2 p = ep[i];
        uint2 u = ((const uint2*)(feat + (size_t)p.x * NODE_ROW))[lane];
        acc4(acc, __int_as_float(p.y), u);
    }
    float ss = acc.x * acc.x + acc.y * acc.y + acc.z * acc.z + acc.w * acc.w;
    #pragma unroll
    for (int o = 16; o > 0; o >>= 1) ss += __shfl_xor(ss, o, 32);
    float sc = 1.0f / fmaxf(sqrtf(ss), 1e-12f);
    uint2 o;
    o.x = pk2(acc.x * sc, acc.y * sc);
    o.y = pk2(acc.z * sc, acc.w * sc);
    ((uint2*)(out + (size_t)node * NODE_ROW))[lane] = o;
}

// ---------------- weight fp32 -> bf16 pre-convert ----------------
__global__ __launch_bounds__(256) void k_cvt(
    const float* __restrict__ W1, const float* __restrict__ W2,
    const float* __restrict__ Win, const float* __restrict__ Wout,
    ushort* __restrict__ dst) {
    int idx = (blockIdx.x * 256 + threadIdx.x) * 4;
    if (idx >= 98304) return;
    const float* s; int off;
    if (idx < 16384)      { s = W1;  off = idx; }
    else if (idx < 32768) { s = W2;  off = idx - 16384; }
    else if (idx < 81920) { s = Win; off = idx - 32768; }
    else                  { s = Wout; off = idx - 81920; }
    float4 f = *(const float4*)(s + off);
    uint2 p;
    p.x = pk2(f.x, f.y);
    p.y = pk2(f.z, f.w);
    *(uint2*)(dst + idx) = p;
}

// ---------------- k_tail: fused gather2 + l2norm + proj + LN/ReLU + attention ----------------
// vs R10: (256,4) -> (256,6). The split-A1 kernel's natural pressure is 48
// arch-VGPR (+~16-24 acc) ~= 70 total, under the ~84 cap at 6 waves/EU, so
// this should raise residency 4 -> ~6 blocks/CU withOUT the spill that hit
// the unsplit kernel at (256,6) (R8) and the split one at (256,8) (R9).
// Pre-committed failure signature: VGPR<48 or WRITE_SIZE>40MB => spilled,
// revert to (256,4).
__global__ __launch_bounds__(256, 6) void k_tail(
    const ushort* __restrict__ hB, const ushort* __restrict__ fbB,
    const int2* __restrict__ ep, const int* __restrict__ start,
    const ushort* __restrict__ W1b, const float* __restrict__ b1,
    const float* __restrict__ g1, const float* __restrict__ be1,
    const ushort* __restrict__ W2b, const float* __restrict__ b2,
    const float* __restrict__ g2, const float* __restrict__ be2,
    const ushort* __restrict__ Winb, const float* __restrict__ binq,
    const ushort* __restrict__ Woutb, const float* __restrict__ bout,
    const float* __restrict__ lng, const float* __restrict__ lnb,
    float* __restrict__ out) {
    __shared__ __align__(16) char pool[18432];
    ushort (*xnP)[136] = (ushort(*)[136])(pool);             // [16][136]
    ushort (*xnQ)[136] = (ushort(*)[136])(pool + 4352);      // [16][136]
    ushort (*obuf)[140] = (ushort(*)[140])(pool);            // [32][140] (aliases xn*)
    ushort (*xb)[136] = (ushort(*)[136])(pool + 8960);       // [32][136]
    float (*yy)[132]  = (float(*)[132])(pool);               // [32][132] (aliases obuf+xb, live after A2a)
    float* stp  = (float*)(pool + 17664);                    // [2 set][16 row][2 wl][2]
    float* mu_s = (float*)(pool + 18176);                    // [32]
    float* rs_s = (float*)(pool + 18304);                    // [32]

    int t = threadIdx.x;
    int lane = t & 63, w = t >> 6;
    int c = lane & 15, quad = lane >> 4;
    int n0 = blockIdx.x * 8;
    size_t pairbase = (size_t)blockIdx.x * 16;

    // ---- Phase G: gather both aggregations for this wave's 2 nodes, l2norm, -> xnP/xnQ
    #pragma unroll
    for (int nl = 0; nl < 2; nl++) {
        int node = n0 + w * 2 + nl;
        int lo = start[node], hi = start[node + 1];
        float4 aP = make_float4(0.f, 0.f, 0.f, 0.f);
        float4 aQ = make_float4(0.f, 0.f, 0.f, 0.f);
        int i = lo;
        for (; i + 3 < hi; i += 4) {
            int2 p0 = ep[i], p1 = ep[i + 1], p2 = ep[i + 2], p3 = ep[i + 3];
            size_t o0 = (size_t)p0.x * NODE_ROW, o1 = (size_t)p1.x * NODE_ROW;
            size_t o2 = (size_t)p2.x * NODE_ROW, o3 = (size_t)p3.x * NODE_ROW;
            uint2 uP0 = ((const uint2*)(hB + o0))[lane];
            uint2 uQ0 = ((const uint2*)(fbB + o0))[lane];
            uint2 uP1 = ((const uint2*)(hB + o1))[lane];
            uint2 uQ1 = ((const uint2*)(fbB + o1))[lane];
            uint2 uP2 = ((const uint2*)(hB + o2))[lane];
            uint2 uQ2 = ((const uint2*)(fbB + o2))[lane];
            uint2 uP3 = ((const uint2*)(hB + o3))[lane];
            uint2 uQ3 = ((const uint2*)(fbB + o3))[lane];
            float w0 = __int_as_float(p0.y), w1 = __int_as_float(p1.y);
            float w2 = __int_as_float(p2.y), w3 = __int_as_float(p3.y);
            acc4(aP, w0, uP0); acc4(aQ, w0, uQ0);
            acc4(aP, w1, uP1); acc4(aQ, w1, uQ1);
            acc4(aP, w2, uP2); acc4(aQ, w2, uQ2);
            acc4(aP, w3, uP3); acc4(aQ, w3, uQ3);
        }
        for (; i < hi; i++) {
            int2 p = ep[i];
            float wv = __int_as_float(p.y);
            size_t off = (size_t)p.x * NODE_ROW;
            uint2 uP = ((const uint2*)(hB + off))[lane];
            uint2 uQ = ((const uint2*)(fbB + off))[lane];
            acc4(aP, wv, uP); acc4(aQ, wv, uQ);
        }
        float ssP = aP.x * aP.x + aP.y * aP.y + aP.z * aP.z + aP.w * aP.w;
        float ssQ = aQ.x * aQ.x + aQ.y * aQ.y + aQ.z * aQ.z + aQ.w * aQ.w;
        #pragma unroll
        for (int o = 16; o > 0; o >>= 1) {
            ssP += __shfl_xor(ssP, o, 32);
            ssQ += __shfl_xor(ssQ, o, 32);
        }
        float scP = 1.0f / fmaxf(sqrtf(ssP), 1e-12f);
        float scQ = 1.0f / fmaxf(sqrtf(ssQ), 1e-12f);
        int rloc = (w * 2 + nl) * 2 + (lane >> 5);
        int col = (lane & 31) * 4;
        uint2 oP, oQ;
        oP.x = pk2(aP.x * scP, aP.y * scP); oP.y = pk2(aP.z * scP, aP.w * scP);
        oQ.x = pk2(aQ.x * scQ, aQ.y * scQ); oQ.y = pk2(aQ.z * scQ, aQ.w * scQ);
        *(uint2*)&xnP[rloc][col] = oP;
        *(uint2*)&xnQ[rloc][col] = oQ;
    }
    __syncthreads();

    // ---- Phase P: proj GEMM into registers + per-wave LN partial stats.
    float yp[4][4];                    // [nt2][rg]
    int setp = w >> 1, wl = w & 1;
    {
        const ushort* Wb = setp ? W2b : W1b;
        const float* bb = setp ? b2 : b1;
        ushort (*xn)[136] = setp ? xnQ : xnP;
        short8 af[4];
        #pragma unroll
        for (int kt = 0; kt < 4; kt++)
            af[kt] = ldfrag(&xn[c][kt * 32 + quad * 8]);
        #pragma unroll
        for (int nt2 = 0; nt2 < 4; nt2++) {
            int j = (wl * 4 + nt2) * 16 + c;
            floatx4 acc = {0.f, 0.f, 0.f, 0.f};
            #pragma unroll
            for (int kt = 0; kt < 4; kt++) {
                short8 bfr = ldfrag(Wb + (size_t)j * 128 + kt * 32 + quad * 8);
                acc = __builtin_amdgcn_mfma_f32_16x16x32_bf16(af[kt], bfr, acc, 0, 0, 0);
            }
            float bj = bb[j];
            #pragma unroll
            for (int rg = 0; rg < 4; rg++)
                yp[nt2][rg] = acc[rg] + bj;
        }
        #pragma unroll
        for (int rg = 0; rg < 4; rg++) {
            float s1 = yp[0][rg] + yp[1][rg] + yp[2][rg] + yp[3][rg];
            float s2 = yp[0][rg]*yp[0][rg] + yp[1][rg]*yp[1][rg]
                     + yp[2][rg]*yp[2][rg] + yp[3][rg]*yp[3][rg];
            s1 += __shfl_xor(s1, 1, 16); s2 += __shfl_xor(s2, 1, 16);
            s1 += __shfl_xor(s1, 2, 16); s2 += __shfl_xor(s2, 2, 16);
            s1 += __shfl_xor(s1, 4, 16); s2 += __shfl_xor(s2, 4, 16);
            s1 += __shfl_xor(s1, 8, 16); s2 += __shfl_xor(s2, 8, 16);
            if (c == 0) {
                int row = quad * 4 + rg;
                stp[((setp * 16 + row) * 2 + wl) * 2 + 0] = s1;
                stp[((setp * 16 + row) * 2 + wl) * 2 + 1] = s2;
            }
        }
    }
    __syncthreads();

    // ---- Phase L: finalize LN in registers, ReLU, write xb (bf16)
    {
        const float* gsrc = setp ? g2 : g1;
        const float* bsrc = setp ? be2 : be1;
        float ggv[4], bbv[4];
        #pragma unroll
        for (int nt2 = 0; nt2 < 4; nt2++) {
            int j = (wl * 4 + nt2) * 16 + c;
            ggv[nt2] = gsrc[j];
            bbv[nt2] = bsrc[j];
        }
        #pragma unroll
        for (int rg = 0; rg < 4; rg++) {
            int row = quad * 4 + rg;
            int base = ((setp * 16 + row) * 2) * 2;
            float s1 = stp[base + 0] + stp[base + 2];
            float s2 = stp[base + 1] + stp[base + 3];
            float mu = s1 * (1.0f / 128.0f);
            float var = s2 * (1.0f / 128.0f) - mu * mu;
            float rs = rsqrtf(var + 1e-5f);
            #pragma unroll
            for (int nt2 = 0; nt2 < 4; nt2++) {
                int j = (wl * 4 + nt2) * 16 + c;
                float v = fmaxf((yp[nt2][rg] - mu) * rs * ggv[nt2] + bbv[nt2], 0.f);
                xb[row * 2 + setp][j] = f2bf(v);
            }
        }
    }
    __syncthreads();

    // ---- Phase A1: QKV + softmax + a@v, split into QK-pass then V-pass to
    // keep peak live VGPRs low (no spill).
    int jb = w * 32 + c;
    {
        const float qs = 0.17677669529663687f;
        #pragma unroll
        for (int hf = 0; hf < 2; hf++) {
            int rb = hf * 16;
            short8 af[4];
            #pragma unroll
            for (int kt = 0; kt < 4; kt++)
                af[kt] = ldfrag(&xb[rb + c][kt * 32 + quad * 8]);

            // QK pass: 4 accumulators, 4 weight frags per kt
            floatx4 aq0 = {0.f,0.f,0.f,0.f}, aq1 = {0.f,0.f,0.f,0.f};
            floatx4 ak0 = {0.f,0.f,0.f,0.f}, ak1 = {0.f,0.f,0.f,0.f};
            #pragma unroll
            for (int kt = 0; kt < 4; kt++) {
                const ushort* wp = Winb + kt * 32 + quad * 8;
                short8 f0 = ldfrag(wp + (size_t)(jb)       * 128);
                short8 f1 = ldfrag(wp + (size_t)(jb + 16)  * 128);
                short8 f2 = ldfrag(wp + (size_t)(jb + 128) * 128);
                short8 f3 = ldfrag(wp + (size_t)(jb + 144) * 128);
                aq0 = __builtin_amdgcn_mfma_f32_16x16x32_bf16(af[kt], f0, aq0, 0, 0, 0);
                aq1 = __builtin_amdgcn_mfma_f32_16x16x32_bf16(af[kt], f1, aq1, 0, 0, 0);
                ak0 = __builtin_amdgcn_mfma_f32_16x16x32_bf16(af[kt], f2, ak0, 0, 0, 0);
                ak1 = __builtin_amdgcn_mfma_f32_16x16x32_bf16(af[kt], f3, ak1, 0, 0, 0);
            }
            {
                float bq0 = binq[jb],       bq1 = binq[jb + 16];
                float bk0 = binq[jb + 128], bk1 = binq[jb + 144];
                #pragma unroll
                for (int rg = 0; rg < 4; rg++) {
                    aq0[rg] = (aq0[rg] + bq0) * qs;
                    aq1[rg] = (aq1[rg] + bq1) * qs;
                    ak0[rg] += bk0;  ak1[rg] += bk1;
                }
            }
            // scores + softmax -> coefficient regs (aq/ak die here)
            float a00[2], a01[2], a10[2], a11[2];
            #pragma unroll
            for (int pl = 0; pl < 2; pl++) {
                int r0 = 2 * pl, r1 = 2 * pl + 1;
                float p00 = aq0[r0] * ak0[r0] + aq1[r0] * ak1[r0];
                float p01 = aq0[r0] * ak0[r1] + aq1[r0] * ak1[r1];
                float p10 = aq0[r1] * ak0[r0] + aq1[r1] * ak1[r0];
                float p11 = aq0[r1] * ak0[r1] + aq1[r1] * ak1[r1];
                #pragma unroll
                for (int m = 1; m < 16; m <<= 1) {
                    p00 += __shfl_xor(p00, m, 16);
                    p01 += __shfl_xor(p01, m, 16);
                    p10 += __shfl_xor(p10, m, 16);
                    p11 += __shfl_xor(p11, m, 16);
                }
                float mx0 = fmaxf(p00, p01), mx1 = fmaxf(p10, p11);
                float e00 = __expf(p00 - mx0), e01 = __expf(p01 - mx0);
                float e10 = __expf(p10 - mx1), e11 = __expf(p11 - mx1);
                float i0 = 1.f / (e00 + e01), i1 = 1.f / (e10 + e11);
                a00[pl] = e00 * i0; a01[pl] = e01 * i0;
                a10[pl] = e10 * i1; a11[pl] = e11 * i1;
            }
            // V pass: 2 accumulators, 2 weight frags per kt
            floatx4 av0 = {0.f,0.f,0.f,0.f}, av1 = {0.f,0.f,0.f,0.f};
            #pragma unroll
            for (int kt = 0; kt < 4; kt++) {
                const ushort* wp = Winb + kt * 32 + quad * 8;
                short8 f4 = ldfrag(wp + (size_t)(jb + 256) * 128);
                short8 f5 = ldfrag(wp + (size_t)(jb + 272) * 128);
                av0 = __builtin_amdgcn_mfma_f32_16x16x32_bf16(af[kt], f4, av0, 0, 0, 0);
                av1 = __builtin_amdgcn_mfma_f32_16x16x32_bf16(af[kt], f5, av1, 0, 0, 0);
            }
            {
                float bv0 = binq[jb + 256], bv1 = binq[jb + 272];
                #pragma unroll
                for (int rg = 0; rg < 4; rg++) { av0[rg] += bv0; av1[rg] += bv1; }
            }
            #pragma unroll
            for (int pl = 0; pl < 2; pl++) {
                int r0 = 2 * pl, r1 = 2 * pl + 1;
                float o00 = a00[pl] * av0[r0] + a01[pl] * av0[r1];
                float o10 = a10[pl] * av0[r0] + a11[pl] * av0[r1];
                float o01 = a00[pl] * av1[r0] + a01[pl] * av1[r1];
                float o11 = a10[pl] * av1[r0] + a11[pl] * av1[r1];
                int row0 = rb + quad * 4 + r0, row1 = rb + quad * 4 + r1;
                obuf[row0][jb]      = f2bf(o00);
                obuf[row1][jb]      = f2bf(o10);
                obuf[row0][jb + 16] = f2bf(o01);
                obuf[row1][jb + 16] = f2bf(o11);
            }
        }
    }
    __syncthreads();

    // ---- Phase A2a: out-proj MFMA + bias + residual -> registers (reads obuf, xb)
    float y2[2][2][4];                 // [half][nt2][rg]
    {
        #pragma unroll
        for (int hf = 0; hf < 2; hf++) {
            int rb = hf * 16;
            short8 af[4];
            #pragma unroll
            for (int kt = 0; kt < 4; kt++)
                af[kt] = ldfrag(&obuf[rb + c][kt * 32 + quad * 8]);
            #pragma unroll
            for (int nt2 = 0; nt2 < 2; nt2++) {
                int j = (w * 2 + nt2) * 16 + c;
                floatx4 acc = {0.f, 0.f, 0.f, 0.f};
                #pragma unroll
                for (int kt = 0; kt < 4; kt++) {
                    short8 bfr = ldfrag(Woutb + (size_t)j * 128 + kt * 32 + quad * 8);
                    acc = __builtin_amdgcn_mfma_f32_16x16x32_bf16(af[kt], bfr, acc, 0, 0, 0);
                }
                float bj = bout[j];
                #pragma unroll
                for (int rg = 0; rg < 4; rg++) {
                    int row = rb + quad * 4 + rg;
                    y2[hf][nt2][rg] = acc[rg] + bj + bf2f(xb[row][j]);
                }
            }
        }
    }
    __syncthreads();

    // ---- Phase A2b: write yy (aliases obuf/xn and xb — both dead now)
    {
        #pragma unroll
        for (int hf = 0; hf < 2; hf++) {
            #pragma unroll
            for (int nt2 = 0; nt2 < 2; nt2++) {
                int j = (w * 2 + nt2) * 16 + c;
                #pragma unroll
                for (int rg = 0; rg < 4; rg++)
                    yy[hf * 16 + quad * 4 + rg][j] = y2[hf][nt2][rg];
            }
        }
    }
    __syncthreads();

    // ---- Phase A3: LN stats per row on yy (256 threads = 32 rows x 8)
    {
        int r = t >> 3, ii = t & 7;
        float s1 = 0.f, s2 = 0.f;
        const float* yr = &yy[r][ii * 16];
        #pragma unroll
        for (int cc = 0; cc < 16; cc++) { float v = yr[cc]; s1 += v; s2 += v * v; }
        s1 += __shfl_down(s1, 4, 8); s2 += __shfl_down(s2, 4, 8);
        s1 += __shfl_down(s1, 2, 8); s2 += __shfl_down(s2, 2, 8);
        s1 += __shfl_down(s1, 1, 8); s2 += __shfl_down(s2, 1, 8);
        if (ii == 0) {
            float mu = s1 / D;
            float var = s2 / D - mu * mu;
            mu_s[r] = mu; rs_s[r] = rsqrtf(var + 1e-5f);
        }
    }
    __syncthreads();

    // ---- Phase A4: LN apply + mean over P, coalesced output
    if (t < 128) {
        int j = t;
        float gj = lng[j], bj = lnb[j];
        #pragma unroll
        for (int pp = 0; pp < 16; pp++) {
            int r0 = pp * 2, r1 = r0 + 1;
            float v0 = (yy[r0][j] - mu_s[r0]) * rs_s[r0] * gj + bj;
            float v1 = (yy[r1][j] - mu_s[r1]) * rs_s[r1] * gj + bj;
            out[(pairbase + pp) * D + j] = 0.5f * (v0 + v1);
        }
    }
}

extern "C" void kernel_launch(void* const* d_in, const int* in_sizes, int n_in,
                              void* d_out, int out_size, void* d_ws, size_t ws_size,
                              hipStream_t stream) {
    const float* feat_A = (const float*)d_in[0];
    const float* feat_B = (const float*)d_in[1];
    const int*   src_ab = (const int*)d_in[2];
    const int*   dst_ab = (const int*)d_in[3];
    const float* val_ab = (const float*)d_in[4];
    const int*   src_ba = (const int*)d_in[5];
    const int*   dst_ba = (const int*)d_in[6];
    const float* val_ba = (const float*)d_in[7];
    const float* W1 = (const float*)d_in[8];
    const float* b1 = (const float*)d_in[9];
    const float* g1 = (const float*)d_in[10];
    const float* be1 = (const float*)d_in[11];
    const float* W2 = (const float*)d_in[12];
    const float* b2 = (const float*)d_in[13];
    const float* g2 = (const float*)d_in[14];
    const float* be2 = (const float*)d_in[15];
    const float* Win = (const float*)d_in[16];
    const float* binq = (const float*)d_in[17];
    const float* Wout = (const float*)d_in[18];
    const float* bout = (const float*)d_in[19];
    const float* lng = (const float*)d_in[20];
    const float* lnb = (const float*)d_in[21];

    int E  = in_sizes[2];
    int nA = in_sizes[0] / NODE_ROW;   // 30000
    int nB = in_sizes[1] / NODE_ROW;   // 30000
    int rowsA = nA * 2;                // 60000
    size_t nodeElems = (size_t)nA * NODE_ROW;

    // Workspace layout (superset of prior rounds; hA1/hA2/xbuf unused)
    ushort* fbA  = (ushort*)d_ws;
    ushort* fbB  = fbA + nodeElems;
    ushort* hB   = fbB + nodeElems;
    ushort* hA1  = hB + nodeElems;      (void)hA1;
    ushort* hA2  = hA1 + nodeElems;     (void)hA2;
    ushort* xbuf = hA2 + nodeElems;     (void)xbuf;
    ushort* Wbf  = xbuf + (size_t)rowsA * 2 * D;
    ushort* W1b   = Wbf;
    ushort* W2b   = Wbf + 16384;
    ushort* Winb  = Wbf + 32768;
    ushort* Woutb = Wbf + 81920;
    int* cnt_ab   = (int*)(Wbf + 98304);
    int* cnt_ba   = cnt_ab + nB;
    int* start_ab = cnt_ba + nA;
    int* start_ba = start_ab + (nB + 1);
    uintptr_t a = (uintptr_t)(start_ba + (nA + 1));
    a = (a + 15) & ~(uintptr_t)15;
    int2* ep_ab = (int2*)a;
    int2* ep_ba = ep_ab + E;

    int egrid = (E + 255) / 256;
    int n8 = (int)(nodeElems / 8);

    // features fp32 -> bf16 (single launch, both matrices)
    k_f2b2<<<(2 * n8 + 255) / 256, 256, 0, stream>>>(feat_A, feat_B, fbA, fbB, n8);

    // CSR build for both graphs
    hipMemsetAsync(cnt_ab, 0, (size_t)(nA + nB) * sizeof(int), stream);
    k_hist<<<egrid, 256, 0, stream>>>(dst_ab, dst_ba, cnt_ab, cnt_ba, E);
    k_scan2<<<2, 1024, 0, stream>>>(cnt_ab, start_ab, nB, cnt_ba, start_ba, nA);
    k_scatter<<<egrid, 256, 0, stream>>>(src_ab, dst_ab, val_ab,
                                         src_ba, dst_ba, val_ba,
                                         cnt_ab, cnt_ba, ep_ab, ep_ba, E);

    // weights -> bf16
    k_cvt<<<96, 256, 0, stream>>>(W1, W2, Win, Wout, Wbf);

    // pass-1 aggregation (A->B), l2norm -> hB
    k_gather_norm_bf<<<(nB + 3) / 4, 256, 0, stream>>>(fbA, ep_ab, start_ab, hB, nB);

    // fused tail: gather2 (B->A, both P and Q) + l2norm + proj + LN/ReLU + attention
    k_tail<<<nA / 8, 256, 0, stream>>>(hB, fbB, ep_ba, start_ba,
                                       W1b, b1, g1, be1,
                                       W2b, b2, g2, be2,
                                       Winb, binq, Woutb, bout,
                                       lng, lnb, (float*)d_out);
}

// Round 12
// 512.709 us; speedup vs baseline: 1.0095x; 1.0095x over previous
//
#include <hip/hip_runtime.h>

// Problem constants: N_A=N_B=30000, V=2, D=128
#define D 128
#define NODE_ROW 256       // V*D elements per node

typedef __attribute__((ext_vector_type(8))) short short8;
typedef __attribute__((ext_vector_type(4))) float floatx4;

__device__ __forceinline__ ushort f2bf(float f) {
    unsigned int u = __float_as_uint(f);
    u += 0x7fffu + ((u >> 16) & 1u);
    return (ushort)(u >> 16);
}
__device__ __forceinline__ unsigned int pk2(float a, float b) {
    return (unsigned int)f2bf(a) | ((unsigned int)f2bf(b) << 16);
}
__device__ __forceinline__ float bf2f(ushort h) {
    return __uint_as_float(((unsigned int)h) << 16);
}
__device__ __forceinline__ short8 ldfrag(const ushort* p) {
    union { uint4 u; short8 s; } cv;
    cv.u = *(const uint4*)p;
    return cv.s;
}
__device__ __forceinline__ void acc4(float4& a, float w, uint2 u) {
    a.x += w * __uint_as_float(u.x << 16);
    a.y += w * __uint_as_float(u.x & 0xffff0000u);
    a.z += w * __uint_as_float(u.y << 16);
    a.w += w * __uint_as_float(u.y & 0xffff0000u);
}

// ---------------- fp32 -> bf16 feature convert (both matrices, one launch) ----------------
__global__ __launch_bounds__(256) void k_f2b2(
    const float* __restrict__ srcA, const float* __restrict__ srcB,
    ushort* __restrict__ dstA, ushort* __restrict__ dstB, int n8) {
    int i = blockIdx.x * 256 + threadIdx.x;
    const float* s; ushort* d; int k;
    if (i < n8) { s = srcA; d = dstA; k = i; }
    else if (i < 2 * n8) { s = srcB; d = dstB; k = i - n8; }
    else return;
    const float4* sp = (const float4*)s + (size_t)k * 2;
    float4 a = sp[0], b = sp[1];
    uint4 o;
    o.x = pk2(a.x, a.y); o.y = pk2(a.z, a.w);
    o.z = pk2(b.x, b.y); o.w = pk2(b.z, b.w);
    ((uint4*)d)[k] = o;
}

// ---------------- CSR build ----------------

__global__ __launch_bounds__(256) void k_hist(
    const int* __restrict__ dst_ab, const int* __restrict__ dst_ba,
    int* __restrict__ cnt_ab, int* __restrict__ cnt_ba, int E) {
    int i = blockIdx.x * 256 + threadIdx.x;
    if (i >= E) return;
    atomicAdd(&cnt_ab[dst_ab[i]], 1);
    atomicAdd(&cnt_ba[dst_ba[i]], 1);
}

__global__ __launch_bounds__(1024) void k_scan2(
    int* __restrict__ cntB, int* __restrict__ startB, int nB_,
    int* __restrict__ cntA, int* __restrict__ startA, int nA_) {
    __shared__ int part[1024];
    int* cnt; int* start; int n;
    if (blockIdx.x == 0) { cnt = cntB; start = startB; n = nB_; }
    else                 { cnt = cntA; start = startA; n = nA_; }
    int t = threadIdx.x;
    int chunk = (n + 1023) >> 10;
    int lo = min(t * chunk, n), hi = min(lo + chunk, n);
    int s = 0;
    for (int i = lo; i < hi; i++) s += cnt[i];
    part[t] = s;
    __syncthreads();
    for (int d = 1; d < 1024; d <<= 1) {
        int v = (t >= d) ? part[t - d] : 0;
        __syncthreads();
        part[t] += v;
        __syncthreads();
    }
    int off = part[t] - s;
    for (int i = lo; i < hi; i++) {
        int c = cnt[i];
        start[i] = off;
        cnt[i] = off;          // running cursor for k_scatter
        off += c;
    }
    if (t == 1023) start[n] = off;
}

__global__ __launch_bounds__(256) void k_scatter(
    const int* __restrict__ src_ab, const int* __restrict__ dst_ab,
    const float* __restrict__ val_ab,
    const int* __restrict__ src_ba, const int* __restrict__ dst_ba,
    const float* __restrict__ val_ba,
    int* __restrict__ cur_ab, int* __restrict__ cur_ba,
    int2* __restrict__ ep_ab, int2* __restrict__ ep_ba, int E) {
    int i = blockIdx.x * 256 + threadIdx.x;
    if (i >= E) return;
    {
        int pos = atomicAdd(&cur_ab[dst_ab[i]], 1);
        ep_ab[pos] = make_int2(src_ab[i], __float_as_int(val_ab[i]));
    }
    {
        int pos = atomicAdd(&cur_ba[dst_ba[i]], 1);
        ep_ba[pos] = make_int2(src_ba[i], __float_as_int(val_ba[i]));
    }
}

// ---------------- pass 1 gather: aggregate fbA over ab edges, l2norm -> hB ----------------
// 8-edge unroll: 8 outstanding feature loads per lane (was 4). The gather is
// latency-bound (R8/R9/R10: fetch BW scales with waves in flight), and this
// kernel is already TLP-maxed (no LDS, low VGPR) -> MLP is the lever.
__global__ __launch_bounds__(256) void k_gather_norm_bf(
    const ushort* __restrict__ feat, const int2* __restrict__ ep,
    const int* __restrict__ start, ushort* __restrict__ out, int n) {
    int node = blockIdx.x * 4 + (threadIdx.x >> 6);
    if (node >= n) return;
    int lane = threadIdx.x & 63;
    int lo = start[node], hi = start[node + 1];
    float4 acc = make_float4(0.f, 0.f, 0.f, 0.f);
    int i = lo;
    for (; i + 7 < hi; i += 8) {
        int2 p0 = ep[i],     p1 = ep[i + 1], p2 = ep[i + 2], p3 = ep[i + 3];
        int2 p4 = ep[i + 4], p5 = ep[i + 5], p6 = ep[i + 6], p7 = ep[i + 7];
        uint2 u0 = ((const uint2*)(feat + (size_t)p0.x * NODE_ROW))[lane];
        uint2 u1 = ((const uint2*)(feat + (size_t)p1.x * NODE_ROW))[lane];
        uint2 u2 = ((const uint2*)(feat + (size_t)p2.x * NODE_ROW))[lane];
        uint2 u3 = ((const uint2*)(feat + (size_t)p3.x * NODE_ROW))[lane];
        uint2 u4 = ((const uint2*)(feat + (size_t)p4.x * NODE_ROW))[lane];
        uint2 u5 = ((const uint2*)(feat + (size_t)p5.x * NODE_ROW))[lane];
        uint2 u6 = ((const uint2*)(feat + (size_t)p6.x * NODE_ROW))[lane];
        uint2 u7 = ((const uint2*)(feat + (size_t)p7.x * NODE_ROW))[lane];
        acc4(acc, __int_as_float(p0.y), u0);
        acc4(acc, __int_as_float(p1.y), u1);
        acc4(acc, __int_as_float(p2.y), u2);
        acc4(acc, __int_as_float(p3.y), u3);
        acc4(acc, __int_as_float(p4.y), u4);
        acc4(acc, __int_as_float(p5.y), u5);
        acc4(acc, __int_as_float(p6.y), u6);
        acc4(acc, __int_as_float(p7.y), u7);
    }
    for (; i + 3 < hi; i += 4) {
        int2 p0 = ep[i], p1 = ep[i + 1], p2 = ep[i + 2], p3 = ep[i + 3];
        uint2 u0 = ((const uint2*)(feat + (size_t)p0.x * NODE_ROW))[lane];
        uint2 u1 = ((const uint2*)(feat + (size_t)p1.x * NODE_ROW))[lane];
        uint2 u2 = ((const uint2*)(feat + (size_t)p2.x * NODE_ROW))[lane];
        uint2 u3 = ((const uint2*)(feat + (size_t)p3.x * NODE_ROW))[lane];
        acc4(acc, __int_as_float(p0.y), u0);
        acc4(acc, __int_as_float(p1.y), u1);
        acc4(acc, __int_as_float(p2.y), u2);
        acc4(acc, __int_as_float(p3.y), u3);
    }
    for (; i < hi; i++) {
        int2 p = ep[i];
        uint2 u = ((const uint2*)(feat + (size_t)p.x * NODE_ROW))[lane];
        acc4(acc, __int_as_float(p.y), u);
    }
    float ss = acc.x * acc.x + acc.y * acc.y + acc.z * acc.z + acc.w * acc.w;
    #pragma unroll
    for (int o = 16; o > 0; o >>= 1) ss += __shfl_xor(ss, o, 32);
    float sc = 1.0f / fmaxf(sqrtf(ss), 1e-12f);
    uint2 o;
    o.x = pk2(acc.x * sc, acc.y * sc);
    o.y = pk2(acc.z * sc, acc.w * sc);
    ((uint2*)(out + (size_t)node * NODE_ROW))[lane] = o;
}

// ---------------- weight fp32 -> bf16 pre-convert ----------------
__global__ __launch_bounds__(256) void k_cvt(
    const float* __restrict__ W1, const float* __restrict__ W2,
    const float* __restrict__ Win, const float* __restrict__ Wout,
    ushort* __restrict__ dst) {
    int idx = (blockIdx.x * 256 + threadIdx.x) * 4;
    if (idx >= 98304) return;
    const float* s; int off;
    if (idx < 16384)      { s = W1;  off = idx; }
    else if (idx < 32768) { s = W2;  off = idx - 16384; }
    else if (idx < 81920) { s = Win; off = idx - 32768; }
    else                  { s = Wout; off = idx - 81920; }
    float4 f = *(const float4*)(s + off);
    uint2 p;
    p.x = pk2(f.x, f.y);
    p.y = pk2(f.z, f.w);
    *(uint2*)(dst + idx) = p;
}

// ---------------- k_tail: fused gather2 + l2norm + proj + LN/ReLU + attention ----------------
// R10 proven config: 18.4KB LDS, A1 QK/V split, (256,4). VGPR_Count excludes
// the accumulator share of the unified file — true pressure ~110-128, so
// (256,4) (cap 128) is the only spill-free point (R8/R9/R11 all spilled at
// tighter caps; R11: VGPR 40 + WRITE 41MB => reverted).
__global__ __launch_bounds__(256, 4) void k_tail(
    const ushort* __restrict__ hB, const ushort* __restrict__ fbB,
    const int2* __restrict__ ep, const int* __restrict__ start,
    const ushort* __restrict__ W1b, const float* __restrict__ b1,
    const float* __restrict__ g1, const float* __restrict__ be1,
    const ushort* __restrict__ W2b, const float* __restrict__ b2,
    const float* __restrict__ g2, const float* __restrict__ be2,
    const ushort* __restrict__ Winb, const float* __restrict__ binq,
    const ushort* __restrict__ Woutb, const float* __restrict__ bout,
    const float* __restrict__ lng, const float* __restrict__ lnb,
    float* __restrict__ out) {
    __shared__ __align__(16) char pool[18432];
    ushort (*xnP)[136] = (ushort(*)[136])(pool);             // [16][136]
    ushort (*xnQ)[136] = (ushort(*)[136])(pool + 4352);      // [16][136]
    ushort (*obuf)[140] = (ushort(*)[140])(pool);            // [32][140] (aliases xn*)
    ushort (*xb)[136] = (ushort(*)[136])(pool + 8960);       // [32][136]
    float (*yy)[132]  = (float(*)[132])(pool);               // [32][132] (aliases obuf+xb, live after A2a)
    float* stp  = (float*)(pool + 17664);                    // [2 set][16 row][2 wl][2]
    float* mu_s = (float*)(pool + 18176);                    // [32]
    float* rs_s = (float*)(pool + 18304);                    // [32]

    int t = threadIdx.x;
    int lane = t & 63, w = t >> 6;
    int c = lane & 15, quad = lane >> 4;
    int n0 = blockIdx.x * 8;
    size_t pairbase = (size_t)blockIdx.x * 16;

    // ---- Phase G: gather both aggregations for this wave's 2 nodes, l2norm, -> xnP/xnQ
    #pragma unroll
    for (int nl = 0; nl < 2; nl++) {
        int node = n0 + w * 2 + nl;
        int lo = start[node], hi = start[node + 1];
        float4 aP = make_float4(0.f, 0.f, 0.f, 0.f);
        float4 aQ = make_float4(0.f, 0.f, 0.f, 0.f);
        int i = lo;
        for (; i + 3 < hi; i += 4) {
            int2 p0 = ep[i], p1 = ep[i + 1], p2 = ep[i + 2], p3 = ep[i + 3];
            size_t o0 = (size_t)p0.x * NODE_ROW, o1 = (size_t)p1.x * NODE_ROW;
            size_t o2 = (size_t)p2.x * NODE_ROW, o3 = (size_t)p3.x * NODE_ROW;
            uint2 uP0 = ((const uint2*)(hB + o0))[lane];
            uint2 uQ0 = ((const uint2*)(fbB + o0))[lane];
            uint2 uP1 = ((const uint2*)(hB + o1))[lane];
            uint2 uQ1 = ((const uint2*)(fbB + o1))[lane];
            uint2 uP2 = ((const uint2*)(hB + o2))[lane];
            uint2 uQ2 = ((const uint2*)(fbB + o2))[lane];
            uint2 uP3 = ((const uint2*)(hB + o3))[lane];
            uint2 uQ3 = ((const uint2*)(fbB + o3))[lane];
            float w0 = __int_as_float(p0.y), w1 = __int_as_float(p1.y);
            float w2 = __int_as_float(p2.y), w3 = __int_as_float(p3.y);
            acc4(aP, w0, uP0); acc4(aQ, w0, uQ0);
            acc4(aP, w1, uP1); acc4(aQ, w1, uQ1);
            acc4(aP, w2, uP2); acc4(aQ, w2, uQ2);
            acc4(aP, w3, uP3); acc4(aQ, w3, uQ3);
        }
        for (; i < hi; i++) {
            int2 p = ep[i];
            float wv = __int_as_float(p.y);
            size_t off = (size_t)p.x * NODE_ROW;
            uint2 uP = ((const uint2*)(hB + off))[lane];
            uint2 uQ = ((const uint2*)(fbB + off))[lane];
            acc4(aP, wv, uP); acc4(aQ, wv, uQ);
        }
        float ssP = aP.x * aP.x + aP.y * aP.y + aP.z * aP.z + aP.w * aP.w;
        float ssQ = aQ.x * aQ.x + aQ.y * aQ.y + aQ.z * aQ.z + aQ.w * aQ.w;
        #pragma unroll
        for (int o = 16; o > 0; o >>= 1) {
            ssP += __shfl_xor(ssP, o, 32);
            ssQ += __shfl_xor(ssQ, o, 32);
        }
        float scP = 1.0f / fmaxf(sqrtf(ssP), 1e-12f);
        float scQ = 1.0f / fmaxf(sqrtf(ssQ), 1e-12f);
        int rloc = (w * 2 + nl) * 2 + (lane >> 5);
        int col = (lane & 31) * 4;
        uint2 oP, oQ;
        oP.x = pk2(aP.x * scP, aP.y * scP); oP.y = pk2(aP.z * scP, aP.w * scP);
        oQ.x = pk2(aQ.x * scQ, aQ.y * scQ); oQ.y = pk2(aQ.z * scQ, aQ.w * scQ);
        *(uint2*)&xnP[rloc][col] = oP;
        *(uint2*)&xnQ[rloc][col] = oQ;
    }
    __syncthreads();

    // ---- Phase P: proj GEMM into registers + per-wave LN partial stats.
    float yp[4][4];                    // [nt2][rg]
    int setp = w >> 1, wl = w & 1;
    {
        const ushort* Wb = setp ? W2b : W1b;
        const float* bb = setp ? b2 : b1;
        ushort (*xn)[136] = setp ? xnQ : xnP;
        short8 af[4];
        #pragma unroll
        for (int kt = 0; kt < 4; kt++)
            af[kt] = ldfrag(&xn[c][kt * 32 + quad * 8]);
        #pragma unroll
        for (int nt2 = 0; nt2 < 4; nt2++) {
            int j = (wl * 4 + nt2) * 16 + c;
            floatx4 acc = {0.f, 0.f, 0.f, 0.f};
            #pragma unroll
            for (int kt = 0; kt < 4; kt++) {
                short8 bfr = ldfrag(Wb + (size_t)j * 128 + kt * 32 + quad * 8);
                acc = __builtin_amdgcn_mfma_f32_16x16x32_bf16(af[kt], bfr, acc, 0, 0, 0);
            }
            float bj = bb[j];
            #pragma unroll
            for (int rg = 0; rg < 4; rg++)
                yp[nt2][rg] = acc[rg] + bj;
        }
        #pragma unroll
        for (int rg = 0; rg < 4; rg++) {
            float s1 = yp[0][rg] + yp[1][rg] + yp[2][rg] + yp[3][rg];
            float s2 = yp[0][rg]*yp[0][rg] + yp[1][rg]*yp[1][rg]
                     + yp[2][rg]*yp[2][rg] + yp[3][rg]*yp[3][rg];
            s1 += __shfl_xor(s1, 1, 16); s2 += __shfl_xor(s2, 1, 16);
            s1 += __shfl_xor(s1, 2, 16); s2 += __shfl_xor(s2, 2, 16);
            s1 += __shfl_xor(s1, 4, 16); s2 += __shfl_xor(s2, 4, 16);
            s1 += __shfl_xor(s1, 8, 16); s2 += __shfl_xor(s2, 8, 16);
            if (c == 0) {
                int row = quad * 4 + rg;
                stp[((setp * 16 + row) * 2 + wl) * 2 + 0] = s1;
                stp[((setp * 16 + row) * 2 + wl) * 2 + 1] = s2;
            }
        }
    }
    __syncthreads();

    // ---- Phase L: finalize LN in registers, ReLU, write xb (bf16)
    {
        const float* gsrc = setp ? g2 : g1;
        const float* bsrc = setp ? be2 : be1;
        float ggv[4], bbv[4];
        #pragma unroll
        for (int nt2 = 0; nt2 < 4; nt2++) {
            int j = (wl * 4 + nt2) * 16 + c;
            ggv[nt2] = gsrc[j];
            bbv[nt2] = bsrc[j];
        }
        #pragma unroll
        for (int rg = 0; rg < 4; rg++) {
            int row = quad * 4 + rg;
            int base = ((setp * 16 + row) * 2) * 2;
            float s1 = stp[base + 0] + stp[base + 2];
            float s2 = stp[base + 1] + stp[base + 3];
            float mu = s1 * (1.0f / 128.0f);
            float var = s2 * (1.0f / 128.0f) - mu * mu;
            float rs = rsqrtf(var + 1e-5f);
            #pragma unroll
            for (int nt2 = 0; nt2 < 4; nt2++) {
                int j = (wl * 4 + nt2) * 16 + c;
                float v = fmaxf((yp[nt2][rg] - mu) * rs * ggv[nt2] + bbv[nt2], 0.f);
                xb[row * 2 + setp][j] = f2bf(v);
            }
        }
    }
    __syncthreads();

    // ---- Phase A1: QKV + softmax + a@v, split into QK-pass then V-pass to
    // keep peak live VGPRs low (no spill).
    int jb = w * 32 + c;
    {
        const float qs = 0.17677669529663687f;
        #pragma unroll
        for (int hf = 0; hf < 2; hf++) {
            int rb = hf * 16;
            short8 af[4];
            #pragma unroll
            for (int kt = 0; kt < 4; kt++)
                af[kt] = ldfrag(&xb[rb + c][kt * 32 + quad * 8]);

            // QK pass: 4 accumulators, 4 weight frags per kt
            floatx4 aq0 = {0.f,0.f,0.f,0.f}, aq1 = {0.f,0.f,0.f,0.f};
            floatx4 ak0 = {0.f,0.f,0.f,0.f}, ak1 = {0.f,0.f,0.f,0.f};
            #pragma unroll
            for (int kt = 0; kt < 4; kt++) {
                const ushort* wp = Winb + kt * 32 + quad * 8;
                short8 f0 = ldfrag(wp + (size_t)(jb)       * 128);
                short8 f1 = ldfrag(wp + (size_t)(jb + 16)  * 128);
                short8 f2 = ldfrag(wp + (size_t)(jb + 128) * 128);
                short8 f3 = ldfrag(wp + (size_t)(jb + 144) * 128);
                aq0 = __builtin_amdgcn_mfma_f32_16x16x32_bf16(af[kt], f0, aq0, 0, 0, 0);
                aq1 = __builtin_amdgcn_mfma_f32_16x16x32_bf16(af[kt], f1, aq1, 0, 0, 0);
                ak0 = __builtin_amdgcn_mfma_f32_16x16x32_bf16(af[kt], f2, ak0, 0, 0, 0);
                ak1 = __builtin_amdgcn_mfma_f32_16x16x32_bf16(af[kt], f3, ak1, 0, 0, 0);
            }
            {
                float bq0 = binq[jb],       bq1 = binq[jb + 16];
                float bk0 = binq[jb + 128], bk1 = binq[jb + 144];
                #pragma unroll
                for (int rg = 0; rg < 4; rg++) {
                    aq0[rg] = (aq0[rg] + bq0) * qs;
                    aq1[rg] = (aq1[rg] + bq1) * qs;
                    ak0[rg] += bk0;  ak1[rg] += bk1;
                }
            }
            // scores + softmax -> coefficient regs (aq/ak die here)
            float a00[2], a01[2], a10[2], a11[2];
            #pragma unroll
            for (int pl = 0; pl < 2; pl++) {
                int r0 = 2 * pl, r1 = 2 * pl + 1;
                float p00 = aq0[r0] * ak0[r0] + aq1[r0] * ak1[r0];
                float p01 = aq0[r0] * ak0[r1] + aq1[r0] * ak1[r1];
                float p10 = aq0[r1] * ak0[r0] + aq1[r1] * ak1[r0];
                float p11 = aq0[r1] * ak0[r1] + aq1[r1] * ak1[r1];
                #pragma unroll
                for (int m = 1; m < 16; m <<= 1) {
                    p00 += __shfl_xor(p00, m, 16);
                    p01 += __shfl_xor(p01, m, 16);
                    p10 += __shfl_xor(p10, m, 16);
                    p11 += __shfl_xor(p11, m, 16);
                }
                float mx0 = fmaxf(p00, p01), mx1 = fmaxf(p10, p11);
                float e00 = __expf(p00 - mx0), e01 = __expf(p01 - mx0);
                float e10 = __expf(p10 - mx1), e11 = __expf(p11 - mx1);
                float i0 = 1.f / (e00 + e01), i1 = 1.f / (e10 + e11);
                a00[pl] = e00 * i0; a01[pl] = e01 * i0;
                a10[pl] = e10 * i1; a11[pl] = e11 * i1;
            }
            // V pass: 2 accumulators, 2 weight frags per kt
            floatx4 av0 = {0.f,0.f,0.f,0.f}, av1 = {0.f,0.f,0.f,0.f};
            #pragma unroll
            for (int kt = 0; kt < 4; kt++) {
                const ushort* wp = Winb + kt * 32 + quad * 8;
                short8 f4 = ldfrag(wp + (size_t)(jb + 256) * 128);
                short8 f5 = ldfrag(wp + (size_t)(jb + 272) * 128);
                av0 = __builtin_amdgcn_mfma_f32_16x16x32_bf16(af[kt], f4, av0, 0, 0, 0);
                av1 = __builtin_amdgcn_mfma_f32_16x16x32_bf16(af[kt], f5, av1, 0, 0, 0);
            }
            {
                float bv0 = binq[jb + 256], bv1 = binq[jb + 272];
                #pragma unroll
                for (int rg = 0; rg < 4; rg++) { av0[rg] += bv0; av1[rg] += bv1; }
            }
            #pragma unroll
            for (int pl = 0; pl < 2; pl++) {
                int r0 = 2 * pl, r1 = 2 * pl + 1;
                float o00 = a00[pl] * av0[r0] + a01[pl] * av0[r1];
                float o10 = a10[pl] * av0[r0] + a11[pl] * av0[r1];
                float o01 = a00[pl] * av1[r0] + a01[pl] * av1[r1];
                float o11 = a10[pl] * av1[r0] + a11[pl] * av1[r1];
                int row0 = rb + quad * 4 + r0, row1 = rb + quad * 4 + r1;
                obuf[row0][jb]      = f2bf(o00);
                obuf[row1][jb]      = f2bf(o10);
                obuf[row0][jb + 16] = f2bf(o01);
                obuf[row1][jb + 16] = f2bf(o11);
            }
        }
    }
    __syncthreads();

    // ---- Phase A2a: out-proj MFMA + bias + residual -> registers (reads obuf, xb)
    float y2[2][2][4];                 // [half][nt2][rg]
    {
        #pragma unroll
        for (int hf = 0; hf < 2; hf++) {
            int rb = hf * 16;
            short8 af[4];
            #pragma unroll
            for (int kt = 0; kt < 4; kt++)
                af[kt] = ldfrag(&obuf[rb + c][kt * 32 + quad * 8]);
            #pragma unroll
            for (int nt2 = 0; nt2 < 2; nt2++) {
                int j = (w * 2 + nt2) * 16 + c;
                floatx4 acc = {0.f, 0.f, 0.f, 0.f};
                #pragma unroll
                for (int kt = 0; kt < 4; kt++) {
                    short8 bfr = ldfrag(Woutb + (size_t)j * 128 + kt * 32 + quad * 8);
                    acc = __builtin_amdgcn_mfma_f32_16x16x32_bf16(af[kt], bfr, acc, 0, 0, 0);
                }
                float bj = bout[j];
                #pragma unroll
                for (int rg = 0; rg < 4; rg++) {
                    int row = rb + quad * 4 + rg;
                    y2[hf][nt2][rg] = acc[rg] + bj + bf2f(xb[row][j]);
                }
            }
        }
    }
    __syncthreads();

    // ---- Phase A2b: write yy (aliases obuf/xn and xb — both dead now)
    {
        #pragma unroll
        for (int hf = 0; hf < 2; hf++) {
            #pragma unroll
            for (int nt2 = 0; nt2 < 2; nt2++) {
                int j = (w * 2 + nt2) * 16 + c;
                #pragma unroll
                for (int rg = 0; rg < 4; rg++)
                    yy[hf * 16 + quad * 4 + rg][j] = y2[hf][nt2][rg];
            }
        }
    }
    __syncthreads();

    // ---- Phase A3: LN stats per row on yy (256 threads = 32 rows x 8)
    {
        int r = t >> 3, ii = t & 7;
        float s1 = 0.f, s2 = 0.f;
        const float* yr = &yy[r][ii * 16];
        #pragma unroll
        for (int cc = 0; cc < 16; cc++) { float v = yr[cc]; s1 += v; s2 += v * v; }
        s1 += __shfl_down(s1, 4, 8); s2 += __shfl_down(s2, 4, 8);
        s1 += __shfl_down(s1, 2, 8); s2 += __shfl_down(s2, 2, 8);
        s1 += __shfl_down(s1, 1, 8); s2 += __shfl_down(s2, 1, 8);
        if (ii == 0) {
            float mu = s1 / D;
            float var = s2 / D - mu * mu;
            mu_s[r] = mu; rs_s[r] = rsqrtf(var + 1e-5f);
        }
    }
    __syncthreads();

    // ---- Phase A4: LN apply + mean over P, coalesced output
    if (t < 128) {
        int j = t;
        float gj = lng[j], bj = lnb[j];
        #pragma unroll
        for (int pp = 0; pp < 16; pp++) {
            int r0 = pp * 2, r1 = r0 + 1;
            float v0 = (yy[r0][j] - mu_s[r0]) * rs_s[r0] * gj + bj;
            float v1 = (yy[r1][j] - mu_s[r1]) * rs_s[r1] * gj + bj;
            out[(pairbase + pp) * D + j] = 0.5f * (v0 + v1);
        }
    }
}

extern "C" void kernel_launch(void* const* d_in, const int* in_sizes, int n_in,
                              void* d_out, int out_size, void* d_ws, size_t ws_size,
                              hipStream_t stream) {
    const float* feat_A = (const float*)d_in[0];
    const float* feat_B = (const float*)d_in[1];
    const int*   src_ab = (const int*)d_in[2];
    const int*   dst_ab = (const int*)d_in[3];
    const float* val_ab = (const float*)d_in[4];
    const int*   src_ba = (const int*)d_in[5];
    const int*   dst_ba = (const int*)d_in[6];
    const float* val_ba = (const float*)d_in[7];
    const float* W1 = (const float*)d_in[8];
    const float* b1 = (const float*)d_in[9];
    const float* g1 = (const float*)d_in[10];
    const float* be1 = (const float*)d_in[11];
    const float* W2 = (const float*)d_in[12];
    const float* b2 = (const float*)d_in[13];
    const float* g2 = (const float*)d_in[14];
    const float* be2 = (const float*)d_in[15];
    const float* Win = (const float*)d_in[16];
    const float* binq = (const float*)d_in[17];
    const float* Wout = (const float*)d_in[18];
    const float* bout = (const float*)d_in[19];
    const float* lng = (const float*)d_in[20];
    const float* lnb = (const float*)d_in[21];

    int E  = in_sizes[2];
    int nA = in_sizes[0] / NODE_ROW;   // 30000
    int nB = in_sizes[1] / NODE_ROW;   // 30000
    int rowsA = nA * 2;                // 60000
    size_t nodeElems = (size_t)nA * NODE_ROW;

    // Workspace layout (superset of prior rounds; hA1/hA2/xbuf unused)
    ushort* fbA  = (ushort*)d_ws;
    ushort* fbB  = fbA + nodeElems;
    ushort* hB   = fbB + nodeElems;
    ushort* hA1  = hB + nodeElems;      (void)hA1;
    ushort* hA2  = hA1 + nodeElems;     (void)hA2;
    ushort* xbuf = hA2 + nodeElems;     (void)xbuf;
    ushort* Wbf  = xbuf + (size_t)rowsA * 2 * D;
    ushort* W1b   = Wbf;
    ushort* W2b   = Wbf + 16384;
    ushort* Winb  = Wbf + 32768;
    ushort* Woutb = Wbf + 81920;
    int* cnt_ab   = (int*)(Wbf + 98304);
    int* cnt_ba   = cnt_ab + nB;
    int* start_ab = cnt_ba + nA;
    int* start_ba = start_ab + (nB + 1);
    uintptr_t a = (uintptr_t)(start_ba + (nA + 1));
    a = (a + 15) & ~(uintptr_t)15;
    int2* ep_ab = (int2*)a;
    int2* ep_ba = ep_ab + E;

    int egrid = (E + 255) / 256;
    int n8 = (int)(nodeElems / 8);

    // features fp32 -> bf16 (single launch, both matrices)
    k_f2b2<<<(2 * n8 + 255) / 256, 256, 0, stream>>>(feat_A, feat_B, fbA, fbB, n8);

    // CSR build for both graphs
    hipMemsetAsync(cnt_ab, 0, (size_t)(nA + nB) * sizeof(int), stream);
    k_hist<<<egrid, 256, 0, stream>>>(dst_ab, dst_ba, cnt_ab, cnt_ba, E);
    k_scan2<<<2, 1024, 0, stream>>>(cnt_ab, start_ab, nB, cnt_ba, start_ba, nA);
    k_scatter<<<egrid, 256, 0, stream>>>(src_ab, dst_ab, val_ab,
                                         src_ba, dst_ba, val_ba,
                                         cnt_ab, cnt_ba, ep_ab, ep_ba, E);

    // weights -> bf16
    k_cvt<<<96, 256, 0, stream>>>(W1, W2, Win, Wout, Wbf);

    // pass-1 aggregation (A->B), l2norm -> hB (8-edge unrolled)
    k_gather_norm_bf<<<(nB + 3) / 4, 256, 0, stream>>>(fbA, ep_ab, start_ab, hB, nB);

    // fused tail: gather2 (B->A, both P and Q) + l2norm + proj + LN/ReLU + attention
    k_tail<<<nA / 8, 256, 0, stream>>>(hB, fbB, ep_ba, start_ba,
                                       W1b, b1, g1, be1,
                                       W2b, b2, g2, be2,
                                       Winb, binq, Woutb, bout,
                                       lng, lnb, (float*)d_out);
}

// Round 13
// 511.627 us; speedup vs baseline: 1.0116x; 1.0021x over previous
//
#include <hip/hip_runtime.h>

// Problem constants: N_A=N_B=30000, V=2, D=128
#define D 128
#define NODE_ROW 256       // V*D elements per node

typedef __attribute__((ext_vector_type(8))) short short8;
typedef __attribute__((ext_vector_type(4))) float floatx4;

__device__ __forceinline__ ushort f2bf(float f) {
    unsigned int u = __float_as_uint(f);
    u += 0x7fffu + ((u >> 16) & 1u);
    return (ushort)(u >> 16);
}
__device__ __forceinline__ unsigned int pk2(float a, float b) {
    return (unsigned int)f2bf(a) | ((unsigned int)f2bf(b) << 16);
}
__device__ __forceinline__ float bf2f(ushort h) {
    return __uint_as_float(((unsigned int)h) << 16);
}
__device__ __forceinline__ short8 ldfrag(const ushort* p) {
    union { uint4 u; short8 s; } cv;
    cv.u = *(const uint4*)p;
    return cv.s;
}
__device__ __forceinline__ void acc4(float4& a, float w, uint2 u) {
    a.x += w * __uint_as_float(u.x << 16);
    a.y += w * __uint_as_float(u.x & 0xffff0000u);
    a.z += w * __uint_as_float(u.y << 16);
    a.w += w * __uint_as_float(u.y & 0xffff0000u);
}

// ---------------- k_prep: fp32->bf16 convert (A,B) + degree histogram, one launch ----------------
__global__ __launch_bounds__(256) void k_prep(
    const float* __restrict__ srcA, const float* __restrict__ srcB,
    ushort* __restrict__ dstA, ushort* __restrict__ dstB, int n8,
    const int* __restrict__ dst_ab, const int* __restrict__ dst_ba,
    int* __restrict__ cnt_ab, int* __restrict__ cnt_ba, int E) {
    int i = blockIdx.x * 256 + threadIdx.x;
    if (i < 2 * n8) {
        const float* s; ushort* d; int k;
        if (i < n8) { s = srcA; d = dstA; k = i; }
        else        { s = srcB; d = dstB; k = i - n8; }
        const float4* sp = (const float4*)s + (size_t)k * 2;
        float4 a = sp[0], b = sp[1];
        uint4 o;
        o.x = pk2(a.x, a.y); o.y = pk2(a.z, a.w);
        o.z = pk2(b.x, b.y); o.w = pk2(b.z, b.w);
        ((uint4*)d)[k] = o;
    } else {
        int e = i - 2 * n8;
        if (e < E) {
            atomicAdd(&cnt_ab[dst_ab[e]], 1);
            atomicAdd(&cnt_ba[dst_ba[e]], 1);
        }
    }
}

// ---------------- k_scan2cvt: dual prefix scan (blocks 0,1) + weight cvt (blocks 2..25) ----------------
__global__ __launch_bounds__(1024) void k_scan2cvt(
    int* __restrict__ cntB, int* __restrict__ startB, int nB_,
    int* __restrict__ cntA, int* __restrict__ startA, int nA_,
    const float* __restrict__ W1, const float* __restrict__ W2,
    const float* __restrict__ Win, const float* __restrict__ Wout,
    ushort* __restrict__ wdst) {
    __shared__ int part[1024];
    if (blockIdx.x >= 2) {
        // weight fp32 -> bf16 (24 blocks x 1024 threads x 4 floats = 98304)
        int idx = ((blockIdx.x - 2) * 1024 + threadIdx.x) * 4;
        if (idx >= 98304) return;
        const float* s; int off;
        if (idx < 16384)      { s = W1;  off = idx; }
        else if (idx < 32768) { s = W2;  off = idx - 16384; }
        else if (idx < 81920) { s = Win; off = idx - 32768; }
        else                  { s = Wout; off = idx - 81920; }
        float4 f = *(const float4*)(s + off);
        uint2 p;
        p.x = pk2(f.x, f.y);
        p.y = pk2(f.z, f.w);
        *(uint2*)(wdst + idx) = p;
        return;
    }
    int* cnt; int* start; int n;
    if (blockIdx.x == 0) { cnt = cntB; start = startB; n = nB_; }
    else                 { cnt = cntA; start = startA; n = nA_; }
    int t = threadIdx.x;
    int chunk = (n + 1023) >> 10;
    int lo = min(t * chunk, n), hi = min(lo + chunk, n);
    int s = 0;
    for (int i = lo; i < hi; i++) s += cnt[i];
    part[t] = s;
    __syncthreads();
    for (int d = 1; d < 1024; d <<= 1) {
        int v = (t >= d) ? part[t - d] : 0;
        __syncthreads();
        part[t] += v;
        __syncthreads();
    }
    int off = part[t] - s;
    for (int i = lo; i < hi; i++) {
        int c = cnt[i];
        start[i] = off;
        cnt[i] = off;          // running cursor for k_scatter
        off += c;
    }
    if (t == 1023) start[n] = off;
}

// scatter with absolute cursors (cnt holds start offsets after scan)
__global__ __launch_bounds__(256) void k_scatter(
    const int* __restrict__ src_ab, const int* __restrict__ dst_ab,
    const float* __restrict__ val_ab,
    const int* __restrict__ src_ba, const int* __restrict__ dst_ba,
    const float* __restrict__ val_ba,
    int* __restrict__ cur_ab, int* __restrict__ cur_ba,
    int2* __restrict__ ep_ab, int2* __restrict__ ep_ba, int E) {
    int i = blockIdx.x * 256 + threadIdx.x;
    if (i >= E) return;
    {
        int pos = atomicAdd(&cur_ab[dst_ab[i]], 1);
        ep_ab[pos] = make_int2(src_ab[i], __float_as_int(val_ab[i]));
    }
    {
        int pos = atomicAdd(&cur_ba[dst_ba[i]], 1);
        ep_ba[pos] = make_int2(src_ba[i], __float_as_int(val_ba[i]));
    }
}

// ---------------- pass 1 gather: aggregate fbA over ab edges, l2norm -> hB ----------------
__global__ __launch_bounds__(256) void k_gather_norm_bf(
    const ushort* __restrict__ feat, const int2* __restrict__ ep,
    const int* __restrict__ start, ushort* __restrict__ out, int n) {
    int node = blockIdx.x * 4 + (threadIdx.x >> 6);
    if (node >= n) return;
    int lane = threadIdx.x & 63;
    int lo = start[node], hi = start[node + 1];
    float4 acc = make_float4(0.f, 0.f, 0.f, 0.f);
    int i = lo;
    for (; i + 7 < hi; i += 8) {
        int2 p0 = ep[i],     p1 = ep[i + 1], p2 = ep[i + 2], p3 = ep[i + 3];
        int2 p4 = ep[i + 4], p5 = ep[i + 5], p6 = ep[i + 6], p7 = ep[i + 7];
        uint2 u0 = ((const uint2*)(feat + (size_t)p0.x * NODE_ROW))[lane];
        uint2 u1 = ((const uint2*)(feat + (size_t)p1.x * NODE_ROW))[lane];
        uint2 u2 = ((const uint2*)(feat + (size_t)p2.x * NODE_ROW))[lane];
        uint2 u3 = ((const uint2*)(feat + (size_t)p3.x * NODE_ROW))[lane];
        uint2 u4 = ((const uint2*)(feat + (size_t)p4.x * NODE_ROW))[lane];
        uint2 u5 = ((const uint2*)(feat + (size_t)p5.x * NODE_ROW))[lane];
        uint2 u6 = ((const uint2*)(feat + (size_t)p6.x * NODE_ROW))[lane];
        uint2 u7 = ((const uint2*)(feat + (size_t)p7.x * NODE_ROW))[lane];
        acc4(acc, __int_as_float(p0.y), u0);
        acc4(acc, __int_as_float(p1.y), u1);
        acc4(acc, __int_as_float(p2.y), u2);
        acc4(acc, __int_as_float(p3.y), u3);
        acc4(acc, __int_as_float(p4.y), u4);
        acc4(acc, __int_as_float(p5.y), u5);
        acc4(acc, __int_as_float(p6.y), u6);
        acc4(acc, __int_as_float(p7.y), u7);
    }
    for (; i + 3 < hi; i += 4) {
        int2 p0 = ep[i], p1 = ep[i + 1], p2 = ep[i + 2], p3 = ep[i + 3];
        uint2 u0 = ((const uint2*)(feat + (size_t)p0.x * NODE_ROW))[lane];
        uint2 u1 = ((const uint2*)(feat + (size_t)p1.x * NODE_ROW))[lane];
        uint2 u2 = ((const uint2*)(feat + (size_t)p2.x * NODE_ROW))[lane];
        uint2 u3 = ((const uint2*)(feat + (size_t)p3.x * NODE_ROW))[lane];
        acc4(acc, __int_as_float(p0.y), u0);
        acc4(acc, __int_as_float(p1.y), u1);
        acc4(acc, __int_as_float(p2.y), u2);
        acc4(acc, __int_as_float(p3.y), u3);
    }
    for (; i < hi; i++) {
        int2 p = ep[i];
        uint2 u = ((const uint2*)(feat + (size_t)p.x * NODE_ROW))[lane];
        acc4(acc, __int_as_float(p.y), u);
    }
    float ss = acc.x * acc.x + acc.y * acc.y + acc.z * acc.z + acc.w * acc.w;
    #pragma unroll
    for (int o = 16; o > 0; o >>= 1) ss += __shfl_xor(ss, o, 32);
    float sc = 1.0f / fmaxf(sqrtf(ss), 1e-12f);
    uint2 o;
    o.x = pk2(acc.x * sc, acc.y * sc);
    o.y = pk2(acc.z * sc, acc.w * sc);
    ((uint2*)(out + (size_t)node * NODE_ROW))[lane] = o;
}

// ---------------- k_tail: fused gather2 + l2norm + proj + LN/ReLU + attention ----------------
// R10/R12 proven config: 18.4KB LDS, A1 QK/V split, (256,4). VGPR_Count
// excludes the accumulator share of the unified file — true pressure ~110-128,
// so (256,4) (cap 128) is the only spill-free point (R8/R9/R11 spilled).
__global__ __launch_bounds__(256, 4) void k_tail(
    const ushort* __restrict__ hB, const ushort* __restrict__ fbB,
    const int2* __restrict__ ep, const int* __restrict__ start,
    const ushort* __restrict__ W1b, const float* __restrict__ b1,
    const float* __restrict__ g1, const float* __restrict__ be1,
    const ushort* __restrict__ W2b, const float* __restrict__ b2,
    const float* __restrict__ g2, const float* __restrict__ be2,
    const ushort* __restrict__ Winb, const float* __restrict__ binq,
    const ushort* __restrict__ Woutb, const float* __restrict__ bout,
    const float* __restrict__ lng, const float* __restrict__ lnb,
    float* __restrict__ out) {
    __shared__ __align__(16) char pool[18432];
    ushort (*xnP)[136] = (ushort(*)[136])(pool);             // [16][136]
    ushort (*xnQ)[136] = (ushort(*)[136])(pool + 4352);      // [16][136]
    ushort (*obuf)[140] = (ushort(*)[140])(pool);            // [32][140] (aliases xn*)
    ushort (*xb)[136] = (ushort(*)[136])(pool + 8960);       // [32][136]
    float (*yy)[132]  = (float(*)[132])(pool);               // [32][132] (aliases obuf+xb, live after A2a)
    float* stp  = (float*)(pool + 17664);                    // [2 set][16 row][2 wl][2]
    float* mu_s = (float*)(pool + 18176);                    // [32]
    float* rs_s = (float*)(pool + 18304);                    // [32]

    int t = threadIdx.x;
    int lane = t & 63, w = t >> 6;
    int c = lane & 15, quad = lane >> 4;
    int n0 = blockIdx.x * 8;
    size_t pairbase = (size_t)blockIdx.x * 16;

    // ---- Phase G: gather both aggregations for this wave's 2 nodes, l2norm, -> xnP/xnQ
    #pragma unroll
    for (int nl = 0; nl < 2; nl++) {
        int node = n0 + w * 2 + nl;
        int lo = start[node], hi = start[node + 1];
        float4 aP = make_float4(0.f, 0.f, 0.f, 0.f);
        float4 aQ = make_float4(0.f, 0.f, 0.f, 0.f);
        int i = lo;
        for (; i + 3 < hi; i += 4) {
            int2 p0 = ep[i], p1 = ep[i + 1], p2 = ep[i + 2], p3 = ep[i + 3];
            size_t o0 = (size_t)p0.x * NODE_ROW, o1 = (size_t)p1.x * NODE_ROW;
            size_t o2 = (size_t)p2.x * NODE_ROW, o3 = (size_t)p3.x * NODE_ROW;
            uint2 uP0 = ((const uint2*)(hB + o0))[lane];
            uint2 uQ0 = ((const uint2*)(fbB + o0))[lane];
            uint2 uP1 = ((const uint2*)(hB + o1))[lane];
            uint2 uQ1 = ((const uint2*)(fbB + o1))[lane];
            uint2 uP2 = ((const uint2*)(hB + o2))[lane];
            uint2 uQ2 = ((const uint2*)(fbB + o2))[lane];
            uint2 uP3 = ((const uint2*)(hB + o3))[lane];
            uint2 uQ3 = ((const uint2*)(fbB + o3))[lane];
            float w0 = __int_as_float(p0.y), w1 = __int_as_float(p1.y);
            float w2 = __int_as_float(p2.y), w3 = __int_as_float(p3.y);
            acc4(aP, w0, uP0); acc4(aQ, w0, uQ0);
            acc4(aP, w1, uP1); acc4(aQ, w1, uQ1);
            acc4(aP, w2, uP2); acc4(aQ, w2, uQ2);
            acc4(aP, w3, uP3); acc4(aQ, w3, uQ3);
        }
        for (; i < hi; i++) {
            int2 p = ep[i];
            float wv = __int_as_float(p.y);
            size_t off = (size_t)p.x * NODE_ROW;
            uint2 uP = ((const uint2*)(hB + off))[lane];
            uint2 uQ = ((const uint2*)(fbB + off))[lane];
            acc4(aP, wv, uP); acc4(aQ, wv, uQ);
        }
        float ssP = aP.x * aP.x + aP.y * aP.y + aP.z * aP.z + aP.w * aP.w;
        float ssQ = aQ.x * aQ.x + aQ.y * aQ.y + aQ.z * aQ.z + aQ.w * aQ.w;
        #pragma unroll
        for (int o = 16; o > 0; o >>= 1) {
            ssP += __shfl_xor(ssP, o, 32);
            ssQ += __shfl_xor(ssQ, o, 32);
        }
        float scP = 1.0f / fmaxf(sqrtf(ssP), 1e-12f);
        float scQ = 1.0f / fmaxf(sqrtf(ssQ), 1e-12f);
        int rloc = (w * 2 + nl) * 2 + (lane >> 5);
        int col = (lane & 31) * 4;
        uint2 oP, oQ;
        oP.x = pk2(aP.x * scP, aP.y * scP); oP.y = pk2(aP.z * scP, aP.w * scP);
        oQ.x = pk2(aQ.x * scQ, aQ.y * scQ); oQ.y = pk2(aQ.z * scQ, aQ.w * scQ);
        *(uint2*)&xnP[rloc][col] = oP;
        *(uint2*)&xnQ[rloc][col] = oQ;
    }
    __syncthreads();

    // ---- Phase P: proj GEMM into registers + per-wave LN partial stats.
    float yp[4][4];                    // [nt2][rg]
    int setp = w >> 1, wl = w & 1;
    {
        const ushort* Wb = setp ? W2b : W1b;
        const float* bb = setp ? b2 : b1;
        ushort (*xn)[136] = setp ? xnQ : xnP;
        short8 af[4];
        #pragma unroll
        for (int kt = 0; kt < 4; kt++)
            af[kt] = ldfrag(&xn[c][kt * 32 + quad * 8]);
        #pragma unroll
        for (int nt2 = 0; nt2 < 4; nt2++) {
            int j = (wl * 4 + nt2) * 16 + c;
            floatx4 acc = {0.f, 0.f, 0.f, 0.f};
            #pragma unroll
            for (int kt = 0; kt < 4; kt++) {
                short8 bfr = ldfrag(Wb + (size_t)j * 128 + kt * 32 + quad * 8);
                acc = __builtin_amdgcn_mfma_f32_16x16x32_bf16(af[kt], bfr, acc, 0, 0, 0);
            }
            float bj = bb[j];
            #pragma unroll
            for (int rg = 0; rg < 4; rg++)
                yp[nt2][rg] = acc[rg] + bj;
        }
        #pragma unroll
        for (int rg = 0; rg < 4; rg++) {
            float s1 = yp[0][rg] + yp[1][rg] + yp[2][rg] + yp[3][rg];
            float s2 = yp[0][rg]*yp[0][rg] + yp[1][rg]*yp[1][rg]
                     + yp[2][rg]*yp[2][rg] + yp[3][rg]*yp[3][rg];
            s1 += __shfl_xor(s1, 1, 16); s2 += __shfl_xor(s2, 1, 16);
            s1 += __shfl_xor(s1, 2, 16); s2 += __shfl_xor(s2, 2, 16);
            s1 += __shfl_xor(s1, 4, 16); s2 += __shfl_xor(s2, 4, 16);
            s1 += __shfl_xor(s1, 8, 16); s2 += __shfl_xor(s2, 8, 16);
            if (c == 0) {
                int row = quad * 4 + rg;
                stp[((setp * 16 + row) * 2 + wl) * 2 + 0] = s1;
                stp[((setp * 16 + row) * 2 + wl) * 2 + 1] = s2;
            }
        }
    }
    __syncthreads();

    // ---- Phase L: finalize LN in registers, ReLU, write xb (bf16)
    {
        const float* gsrc = setp ? g2 : g1;
        const float* bsrc = setp ? be2 : be1;
        float ggv[4], bbv[4];
        #pragma unroll
        for (int nt2 = 0; nt2 < 4; nt2++) {
            int j = (wl * 4 + nt2) * 16 + c;
            ggv[nt2] = gsrc[j];
            bbv[nt2] = bsrc[j];
        }
        #pragma unroll
        for (int rg = 0; rg < 4; rg++) {
            int row = quad * 4 + rg;
            int base = ((setp * 16 + row) * 2) * 2;
            float s1 = stp[base + 0] + stp[base + 2];
            float s2 = stp[base + 1] + stp[base + 3];
            float mu = s1 * (1.0f / 128.0f);
            float var = s2 * (1.0f / 128.0f) - mu * mu;
            float rs = rsqrtf(var + 1e-5f);
            #pragma unroll
            for (int nt2 = 0; nt2 < 4; nt2++) {
                int j = (wl * 4 + nt2) * 16 + c;
                float v = fmaxf((yp[nt2][rg] - mu) * rs * ggv[nt2] + bbv[nt2], 0.f);
                xb[row * 2 + setp][j] = f2bf(v);
            }
        }
    }
    __syncthreads();

    // ---- Phase A1: QKV + softmax + a@v, split into QK-pass then V-pass to
    // keep peak live VGPRs low (no spill).
    int jb = w * 32 + c;
    {
        const float qs = 0.17677669529663687f;
        #pragma unroll
        for (int hf = 0; hf < 2; hf++) {
            int rb = hf * 16;
            short8 af[4];
            #pragma unroll
            for (int kt = 0; kt < 4; kt++)
                af[kt] = ldfrag(&xb[rb + c][kt * 32 + quad * 8]);

            // QK pass: 4 accumulators, 4 weight frags per kt
            floatx4 aq0 = {0.f,0.f,0.f,0.f}, aq1 = {0.f,0.f,0.f,0.f};
            floatx4 ak0 = {0.f,0.f,0.f,0.f}, ak1 = {0.f,0.f,0.f,0.f};
            #pragma unroll
            for (int kt = 0; kt < 4; kt++) {
                const ushort* wp = Winb + kt * 32 + quad * 8;
                short8 f0 = ldfrag(wp + (size_t)(jb)       * 128);
                short8 f1 = ldfrag(wp + (size_t)(jb + 16)  * 128);
                short8 f2 = ldfrag(wp + (size_t)(jb + 128) * 128);
                short8 f3 = ldfrag(wp + (size_t)(jb + 144) * 128);
                aq0 = __builtin_amdgcn_mfma_f32_16x16x32_bf16(af[kt], f0, aq0, 0, 0, 0);
                aq1 = __builtin_amdgcn_mfma_f32_16x16x32_bf16(af[kt], f1, aq1, 0, 0, 0);
                ak0 = __builtin_amdgcn_mfma_f32_16x16x32_bf16(af[kt], f2, ak0, 0, 0, 0);
                ak1 = __builtin_amdgcn_mfma_f32_16x16x32_bf16(af[kt], f3, ak1, 0, 0, 0);
            }
            {
                float bq0 = binq[jb],       bq1 = binq[jb + 16];
                float bk0 = binq[jb + 128], bk1 = binq[jb + 144];
                #pragma unroll
                for (int rg = 0; rg < 4; rg++) {
                    aq0[rg] = (aq0[rg] + bq0) * qs;
                    aq1[rg] = (aq1[rg] + bq1) * qs;
                    ak0[rg] += bk0;  ak1[rg] += bk1;
                }
            }
            // scores + softmax -> coefficient regs (aq/ak die here)
            float a00[2], a01[2], a10[2], a11[2];
            #pragma unroll
            for (int pl = 0; pl < 2; pl++) {
                int r0 = 2 * pl, r1 = 2 * pl + 1;
                float p00 = aq0[r0] * ak0[r0] + aq1[r0] * ak1[r0];
                float p01 = aq0[r0] * ak0[r1] + aq1[r0] * ak1[r1];
                float p10 = aq0[r1] * ak0[r0] + aq1[r1] * ak1[r0];
                float p11 = aq0[r1] * ak0[r1] + aq1[r1] * ak1[r1];
                #pragma unroll
                for (int m = 1; m < 16; m <<= 1) {
                    p00 += __shfl_xor(p00, m, 16);
                    p01 += __shfl_xor(p01, m, 16);
                    p10 += __shfl_xor(p10, m, 16);
                    p11 += __shfl_xor(p11, m, 16);
                }
                float mx0 = fmaxf(p00, p01), mx1 = fmaxf(p10, p11);
                float e00 = __expf(p00 - mx0), e01 = __expf(p01 - mx0);
                float e10 = __expf(p10 - mx1), e11 = __expf(p11 - mx1);
                float i0 = 1.f / (e00 + e01), i1 = 1.f / (e10 + e11);
                a00[pl] = e00 * i0; a01[pl] = e01 * i0;
                a10[pl] = e10 * i1; a11[pl] = e11 * i1;
            }
            // V pass: 2 accumulators, 2 weight frags per kt
            floatx4 av0 = {0.f,0.f,0.f,0.f}, av1 = {0.f,0.f,0.f,0.f};
            #pragma unroll
            for (int kt = 0; kt < 4; kt++) {
                const ushort* wp = Winb + kt * 32 + quad * 8;
                short8 f4 = ldfrag(wp + (size_t)(jb + 256) * 128);
                short8 f5 = ldfrag(wp + (size_t)(jb + 272) * 128);
                av0 = __builtin_amdgcn_mfma_f32_16x16x32_bf16(af[kt], f4, av0, 0, 0, 0);
                av1 = __builtin_amdgcn_mfma_f32_16x16x32_bf16(af[kt], f5, av1, 0, 0, 0);
            }
            {
                float bv0 = binq[jb + 256], bv1 = binq[jb + 272];
                #pragma unroll
                for (int rg = 0; rg < 4; rg++) { av0[rg] += bv0; av1[rg] += bv1; }
            }
            #pragma unroll
            for (int pl = 0; pl < 2; pl++) {
                int r0 = 2 * pl, r1 = 2 * pl + 1;
                float o00 = a00[pl] * av0[r0] + a01[pl] * av0[r1];
                float o10 = a10[pl] * av0[r0] + a11[pl] * av0[r1];
                float o01 = a00[pl] * av1[r0] + a01[pl] * av1[r1];
                float o11 = a10[pl] * av1[r0] + a11[pl] * av1[r1];
                int row0 = rb + quad * 4 + r0, row1 = rb + quad * 4 + r1;
                obuf[row0][jb]      = f2bf(o00);
                obuf[row1][jb]      = f2bf(o10);
                obuf[row0][jb + 16] = f2bf(o01);
                obuf[row1][jb + 16] = f2bf(o11);
            }
        }
    }
    __syncthreads();

    // ---- Phase A2a: out-proj MFMA + bias + residual -> registers (reads obuf, xb)
    float y2[2][2][4];                 // [half][nt2][rg]
    {
        #pragma unroll
        for (int hf = 0; hf < 2; hf++) {
            int rb = hf * 16;
            short8 af[4];
            #pragma unroll
            for (int kt = 0; kt < 4; kt++)
                af[kt] = ldfrag(&obuf[rb + c][kt * 32 + quad * 8]);
            #pragma unroll
            for (int nt2 = 0; nt2 < 2; nt2++) {
                int j = (w * 2 + nt2) * 16 + c;
                floatx4 acc = {0.f, 0.f, 0.f, 0.f};
                #pragma unroll
                for (int kt = 0; kt < 4; kt++) {
                    short8 bfr = ldfrag(Woutb + (size_t)j * 128 + kt * 32 + quad * 8);
                    acc = __builtin_amdgcn_mfma_f32_16x16x32_bf16(af[kt], bfr, acc, 0, 0, 0);
                }
                float bj = bout[j];
                #pragma unroll
                for (int rg = 0; rg < 4; rg++) {
                    int row = rb + quad * 4 + rg;
                    y2[hf][nt2][rg] = acc[rg] + bj + bf2f(xb[row][j]);
                }
            }
        }
    }
    __syncthreads();

    // ---- Phase A2b: write yy (aliases obuf/xn and xb — both dead now)
    {
        #pragma unroll
        for (int hf = 0; hf < 2; hf++) {
            #pragma unroll
            for (int nt2 = 0; nt2 < 2; nt2++) {
                int j = (w * 2 + nt2) * 16 + c;
                #pragma unroll
                for (int rg = 0; rg < 4; rg++)
                    yy[hf * 16 + quad * 4 + rg][j] = y2[hf][nt2][rg];
            }
        }
    }
    __syncthreads();

    // ---- Phase A3: LN stats per row on yy (256 threads = 32 rows x 8)
    {
        int r = t >> 3, ii = t & 7;
        float s1 = 0.f, s2 = 0.f;
        const float* yr = &yy[r][ii * 16];
        #pragma unroll
        for (int cc = 0; cc < 16; cc++) { float v = yr[cc]; s1 += v; s2 += v * v; }
        s1 += __shfl_down(s1, 4, 8); s2 += __shfl_down(s2, 4, 8);
        s1 += __shfl_down(s1, 2, 8); s2 += __shfl_down(s2, 2, 8);
        s1 += __shfl_down(s1, 1, 8); s2 += __shfl_down(s2, 1, 8);
        if (ii == 0) {
            float mu = s1 / D;
            float var = s2 / D - mu * mu;
            mu_s[r] = mu; rs_s[r] = rsqrtf(var + 1e-5f);
        }
    }
    __syncthreads();

    // ---- Phase A4: LN apply + mean over P, coalesced output
    if (t < 128) {
        int j = t;
        float gj = lng[j], bj = lnb[j];
        #pragma unroll
        for (int pp = 0; pp < 16; pp++) {
            int r0 = pp * 2, r1 = r0 + 1;
            float v0 = (yy[r0][j] - mu_s[r0]) * rs_s[r0] * gj + bj;
            float v1 = (yy[r1][j] - mu_s[r1]) * rs_s[r1] * gj + bj;
            out[(pairbase + pp) * D + j] = 0.5f * (v0 + v1);
        }
    }
}

extern "C" void kernel_launch(void* const* d_in, const int* in_sizes, int n_in,
                              void* d_out, int out_size, void* d_ws, size_t ws_size,
                              hipStream_t stream) {
    const float* feat_A = (const float*)d_in[0];
    const float* feat_B = (const float*)d_in[1];
    const int*   src_ab = (const int*)d_in[2];
    const int*   dst_ab = (const int*)d_in[3];
    const float* val_ab = (const float*)d_in[4];
    const int*   src_ba = (const int*)d_in[5];
    const int*   dst_ba = (const int*)d_in[6];
    const float* val_ba = (const float*)d_in[7];
    const float* W1 = (const float*)d_in[8];
    const float* b1 = (const float*)d_in[9];
    const float* g1 = (const float*)d_in[10];
    const float* be1 = (const float*)d_in[11];
    const float* W2 = (const float*)d_in[12];
    const float* b2 = (const float*)d_in[13];
    const float* g2 = (const float*)d_in[14];
    const float* be2 = (const float*)d_in[15];
    const float* Win = (const float*)d_in[16];
    const float* binq = (const float*)d_in[17];
    const float* Wout = (const float*)d_in[18];
    const float* bout = (const float*)d_in[19];
    const float* lng = (const float*)d_in[20];
    const float* lnb = (const float*)d_in[21];

    int E  = in_sizes[2];
    int nA = in_sizes[0] / NODE_ROW;   // 30000
    int nB = in_sizes[1] / NODE_ROW;   // 30000
    int rowsA = nA * 2;                // 60000
    size_t nodeElems = (size_t)nA * NODE_ROW;

    // Workspace layout (superset of prior rounds; hA1/hA2/xbuf unused)
    ushort* fbA  = (ushort*)d_ws;
    ushort* fbB  = fbA + nodeElems;
    ushort* hB   = fbB + nodeElems;
    ushort* hA1  = hB + nodeElems;      (void)hA1;
    ushort* hA2  = hA1 + nodeElems;     (void)hA2;
    ushort* xbuf = hA2 + nodeElems;     (void)xbuf;
    ushort* Wbf  = xbuf + (size_t)rowsA * 2 * D;
    ushort* W1b   = Wbf;
    ushort* W2b   = Wbf + 16384;
    ushort* Winb  = Wbf + 32768;
    ushort* Woutb = Wbf + 81920;
    int* cnt_ab   = (int*)(Wbf + 98304);
    int* cnt_ba   = cnt_ab + nB;
    int* start_ab = cnt_ba + nA;
    int* start_ba = start_ab + (nB + 1);
    uintptr_t a = (uintptr_t)(start_ba + (nA + 1));
    a = (a + 15) & ~(uintptr_t)15;
    int2* ep_ab = (int2*)a;
    int2* ep_ba = ep_ab + E;

    int egrid = (E + 255) / 256;
    int n8 = (int)(nodeElems / 8);

    // zero degree counters, then fused convert + histogram
    hipMemsetAsync(cnt_ab, 0, (size_t)(nA + nB) * sizeof(int), stream);
    k_prep<<<(2 * n8 + E + 255) / 256, 256, 0, stream>>>(
        feat_A, feat_B, fbA, fbB, n8, dst_ab, dst_ba, cnt_ab, cnt_ba, E);

    // dual scan (blocks 0,1) + weight cvt (blocks 2..25), one launch
    k_scan2cvt<<<26, 1024, 0, stream>>>(cnt_ab, start_ab, nB, cnt_ba, start_ba, nA,
                                        W1, W2, Win, Wout, Wbf);

    // edge scatter into CSR order
    k_scatter<<<egrid, 256, 0, stream>>>(src_ab, dst_ab, val_ab,
                                         src_ba, dst_ba, val_ba,
                                         cnt_ab, cnt_ba, ep_ab, ep_ba, E);

    // pass-1 aggregation (A->B), l2norm -> hB (8-edge unrolled)
    k_gather_norm_bf<<<(nB + 3) / 4, 256, 0, stream>>>(fbA, ep_ab, start_ab, hB, nB);

    // fused tail: gather2 (B->A, both P and Q) + l2norm + proj + LN/ReLU + attention
    k_tail<<<nA / 8, 256, 0, stream>>>(hB, fbB, ep_ba, start_ba,
                                       W1b, b1, g1, be1,
                                       W2b, b2, g2, be2,
                                       Winb, binq, Woutb, bout,
                                       lng, lnb, (float*)d_out);
}